// Round 6
// baseline (603.183 us; speedup 1.0000x reference)
//
#include <hip/hip_runtime.h>

// TemporalAttention N=8192 D=1024, fp32 in/out, fp16-MFMA internals.
// v6: (a) PV GEMM split-K=2 (z-dim): 1024 blocks -> 4 resident/CU (was 2,
// grid-starved at 512); z0 -> fp32 partial in reused ws, z1 -> d_out; fused
// reduce kernel adds partials and applies invL. (b) stats GEMM BK=64 (16
// K-iters, barriers halved) with XOR-swizzled LDS (chunk ^= row&7) to keep
// ds_read_b128 at free 2-way bank aliasing despite the 128B row stride.

using half8   = __attribute__((ext_vector_type(8))) _Float16;
using half4   = __attribute__((ext_vector_type(4))) _Float16;
using floatx4 = __attribute__((ext_vector_type(4))) float;

__device__ __forceinline__ void gload_lds16(const void* g, void* l) {
  __builtin_amdgcn_global_load_lds((const __attribute__((address_space(1))) void*)g,
                                   (__attribute__((address_space(3))) void*)l,
                                   16, 0, 0);
}

// C[128y.., 128x..] = A(rows, lda) * B(rows, ldb)^T; fp16 in, fp32 accum.
// 128x128 tile, BK=32, 4 waves of 4x4 16x16x32 MFMA.
// BIAS_MODE: 0 none, 1 add per-col, 2 add per-row, 3 MUL per-row.
// OUT_MODE: 0 fp16, 2 fp32.  SWZ: tileY = bflat % gridDim.y (XCD grouping).
// Split-K via gridDim.z: each z handles K columns starting at z*K; output
// base shifted by z*zByteStride.
template<int BIAS_MODE, int OUT_MODE, int SWZ>
__global__ __launch_bounds__(256)
void gemm_bt_k(const _Float16* __restrict__ A, const _Float16* __restrict__ B,
               void* __restrict__ Cout, const float* __restrict__ bias,
               int lda, int ldb, int ldc, int K, float outScale,
               long long zByteStride)
{
  __shared__ __align__(16) _Float16 As[128 * 32];
  __shared__ __align__(16) _Float16 Bs[128 * 32];
  const int tid = threadIdx.x;
  const int w = tid >> 6, lane = tid & 63;
  const int q = lane >> 4, l15 = lane & 15;
  const int wr = w >> 1, wc = w & 1;

  int tx, ty;
  if (SWZ) {
    const int bflat = blockIdx.y * gridDim.x + blockIdx.x;  // dispatch-linear
    ty = bflat % gridDim.y;          // same ty -> same bflat%8 -> same XCD
    tx = bflat / gridDim.y;
  } else {
    tx = blockIdx.x; ty = blockIdx.y;
  }
  const long rowBase = (long)ty * 128;
  const long colBase = (long)tx * 128;
  const long kOff = (long)blockIdx.z * K;
  A += kOff; B += kOff;
  Cout = (void*)((char*)Cout + (long long)blockIdx.z * zByteStride);

  // staging: tile elem e = w*1024 + s*512 + lane*8 -> row e/32, col e%32
  const int e0 = w * 1024 + lane * 8;
  const int r0 = e0 >> 5, c0 = e0 & 31;
  const int r1 = (e0 + 512) >> 5, c1 = (e0 + 512) & 31;
  const _Float16* Ag0 = A + (rowBase + r0) * lda + c0;
  const _Float16* Ag1 = A + (rowBase + r1) * lda + c1;
  const _Float16* Bg0 = B + (colBase + r0) * ldb + c0;
  const _Float16* Bg1 = B + (colBase + r1) * ldb + c1;
  _Float16* Al0 = &As[w * 1024];
  _Float16* Al1 = &As[w * 1024 + 512];
  _Float16* Bl0 = &Bs[w * 1024];
  _Float16* Bl1 = &Bs[w * 1024 + 512];

  floatx4 acc[4][4] = {};

  for (int k0 = 0; k0 < K; k0 += 32) {
    __syncthreads();
    gload_lds16(Ag0, Al0);
    gload_lds16(Ag1, Al1);
    gload_lds16(Bg0, Bl0);
    gload_lds16(Bg1, Bl1);
    Ag0 += 32; Ag1 += 32; Bg0 += 32; Bg1 += 32;
    __syncthreads();
    half8 a[4], b[4];
#pragma unroll
    for (int i = 0; i < 4; ++i)
      a[i] = *(const half8*)&As[(wr * 64 + 16 * i + l15) * 32 + q * 8];
#pragma unroll
    for (int j = 0; j < 4; ++j)
      b[j] = *(const half8*)&Bs[(wc * 64 + 16 * j + l15) * 32 + q * 8];
#pragma unroll
    for (int i = 0; i < 4; ++i)
#pragma unroll
      for (int j = 0; j < 4; ++j)
        acc[i][j] = __builtin_amdgcn_mfma_f32_16x16x32_f16(a[i], b[j], acc[i][j], 0, 0, 0);
  }

#pragma unroll
  for (int i = 0; i < 4; ++i) {
#pragma unroll
    for (int r = 0; r < 4; ++r) {
      const long rowg = rowBase + wr * 64 + 16 * i + q * 4 + r;
#pragma unroll
      for (int j = 0; j < 4; ++j) {
        const long colg = colBase + wc * 64 + 16 * j + l15;
        float v = acc[i][j][r];
        if (BIAS_MODE == 1) v += bias[colg];
        if (BIAS_MODE == 2) v += bias[rowg];
        if (BIAS_MODE == 3) v *= bias[rowg];
        v *= outScale;
        if (OUT_MODE == 2) ((float*)Cout)[rowg * ldc + colg] = v;
        else               ((_Float16*)Cout)[rowg * ldc + colg] = (_Float16)v;
      }
    }
  }
}

// U = exp(qkScale*(Q*K^T) + decay_bias - 4), fp16; per-(row,col-tile) sums.
// BK=64, XOR-swizzled LDS: LDS(row, chunk c) holds global chunk c^(row&7).
__global__ __launch_bounds__(256)
void gemm_stats_k(const _Float16* __restrict__ A, const _Float16* __restrict__ B,
                  const float* __restrict__ ts, _Float16* __restrict__ U,
                  float* __restrict__ part, int lda, int ldb, int N, int K,
                  float qkScale)
{
  __shared__ __align__(16) _Float16 As[128 * 64];
  __shared__ __align__(16) _Float16 Bs[128 * 64];
  __shared__ float trs[128], tcs[128];
  __shared__ float sL[2][2][64];
  const int tid = threadIdx.x;
  const int w = tid >> 6, lane = tid & 63;
  const int q = lane >> 4, l15 = lane & 15;
  const int wr = w >> 1, wc = w & 1;
  const long rowBase = (long)blockIdx.y * 128;
  const long colBase = (long)blockIdx.x * 128;

  if (tid < 128) {
    trs[tid] = ts[rowBase + tid];
    tcs[tid] = ts[colBase + tid];
  }

  // staging: 4 passes/wave/operand; lane elem e = w*2048 + p*512 + lane*8;
  // row = e/64, chunk = (e/8)&7; source chunk = chunk ^ (row&7).
  const _Float16* Ag[4]; const _Float16* Bg[4];
  _Float16* Al[4]; _Float16* Bl[4];
#pragma unroll
  for (int p = 0; p < 4; ++p) {
    const int e = w * 2048 + p * 512 + lane * 8;
    const int row = e >> 6, c = (e >> 3) & 7;
    const int sc = (c ^ (row & 7)) << 3;
    Ag[p] = A + (rowBase + row) * lda + sc;
    Bg[p] = B + (colBase + row) * ldb + sc;
    Al[p] = &As[w * 2048 + p * 512];
    Bl[p] = &Bs[w * 2048 + p * 512];
  }

  floatx4 acc[4][4] = {};

  for (int k0 = 0; k0 < K; k0 += 64) {
    __syncthreads();
#pragma unroll
    for (int p = 0; p < 4; ++p) {
      gload_lds16(Ag[p], Al[p]);
      gload_lds16(Bg[p], Bl[p]);
      Ag[p] += 64; Bg[p] += 64;
    }
    __syncthreads();
#pragma unroll
    for (int kk = 0; kk < 2; ++kk) {
      half8 b[4];
#pragma unroll
      for (int j = 0; j < 4; ++j) {
        const int R = wc * 64 + 16 * j + l15;
        b[j] = *(const half8*)&Bs[R * 64 + (((kk * 4 + q) ^ (R & 7)) << 3)];
      }
#pragma unroll
      for (int i = 0; i < 4; ++i) {
        const int R = wr * 64 + 16 * i + l15;
        const half8 a = *(const half8*)&As[R * 64 + (((kk * 4 + q) ^ (R & 7)) << 3)];
#pragma unroll
        for (int j = 0; j < 4; ++j)
          acc[i][j] = __builtin_amdgcn_mfma_f32_16x16x32_f16(a, b[j], acc[i][j], 0, 0, 0);
      }
    }
  }

  const float inv_td = 1.0f / 86400.0f;
  // u = exp(s - 4); s = qk/32 + log-decay ~ qk/32 - |dt|/TD (exact to 2.2e-6).
#pragma unroll
  for (int i = 0; i < 4; ++i) {
#pragma unroll
    for (int r = 0; r < 4; ++r) {
      const int rowl = wr * 64 + 16 * i + q * 4 + r;
      float ls = 0.0f;
#pragma unroll
      for (int j = 0; j < 4; ++j) {
        const int coll = wc * 64 + 16 * j + l15;
        const float sv = acc[i][j][r] * qkScale
                       - fabsf(trs[rowl] - tcs[coll]) * inv_td - 4.0f;
        const float u = __expf(sv);
        ls += u;
        U[(rowBase + rowl) * (long)N + (colBase + coll)] = (_Float16)u;
      }
      for (int mask = 1; mask <= 8; mask <<= 1)
        ls += __shfl_xor(ls, mask, 64);
      if (l15 == 0) sL[wr][wc][16 * i + 4 * q + r] = ls;
    }
  }
  __syncthreads();
  if (tid < 128) {
    const int wr2 = tid >> 6, rl = tid & 63;
    part[(rowBase + tid) * 64 + blockIdx.x] = sL[wr2][0][rl] + sL[wr2][1][rl];
  }
}

__global__ void combine_k(const float* __restrict__ part, float* __restrict__ invL) {
  const int r = blockIdx.x * 256 + threadIdx.x;
  float L = 0.0f;
  for (int c = 0; c < 64; ++c) L += part[(long)r * 64 + c];
  invL[r] = 1.0f / L;
}

// out = (out + partial) * invL[row], float4 vectorized; ldc = 1024 (D)
__global__ void reduce_k(float* __restrict__ out, const float* __restrict__ part,
                         const float* __restrict__ invL) {
  const long i = ((long)blockIdx.x * 256 + threadIdx.x) * 4;
  const int row = (int)(i >> 10);
  const float s = invL[row];
  float4 o = *(const float4*)(out + i);
  const float4 p4 = *(const float4*)(part + i);
  o.x = (o.x + p4.x) * s;
  o.y = (o.y + p4.y) * s;
  o.z = (o.z + p4.z) * s;
  o.w = (o.w + p4.w) * s;
  *(float4*)(out + i) = o;
}

// fp32 -> fp16, 4/thread
__global__ void cvt_k(const float* __restrict__ in, _Float16* __restrict__ out, int n) {
  const int i = (blockIdx.x * 256 + threadIdx.x) * 4;
  if (i >= n) return;
  const float4 v = *(const float4*)(in + i);
  half4 o = { (_Float16)v.x, (_Float16)v.y, (_Float16)v.z, (_Float16)v.w };
  *(half4*)(out + i) = o;
}

extern "C" void kernel_launch(void* const* d_in, const int* in_sizes, int n_in,
                              void* d_out, int out_size, void* d_ws, size_t ws_size,
                              hipStream_t stream)
{
  (void)in_sizes; (void)n_in; (void)out_size; (void)ws_size;
  const int N = 8192, D = 1024;
  const float* x  = (const float*)d_in[0];
  const float* ts = (const float*)d_in[1];
  const float* Wq = (const float*)d_in[2];
  const float* bq = (const float*)d_in[3];
  const float* Wk = (const float*)d_in[4];
  const float* bk = (const float*)d_in[5];
  const float* Wv = (const float*)d_in[6];
  const float* bv = (const float*)d_in[7];

  char* p = (char*)d_ws;
  auto grab = [&](size_t bytes) {
    char* r = p;
    p += (bytes + 255) & ~(size_t)255;
    return r;
  };
  _Float16* xh    = (_Float16*)grab((size_t)N * D * 2);
  _Float16* wqkh  = (_Float16*)grab((size_t)2 * D * D * 2); // Wq rows then Wk rows
  _Float16* wvh   = (_Float16*)grab((size_t)D * D * 2);
  _Float16* QKcat = (_Float16*)grab((size_t)N * 2 * D * 2); // [N x 2D], Q | K
  _Float16* VTh   = (_Float16*)grab((size_t)D * N * 2);     // V^T [D x N]
  _Float16* Uh    = (_Float16*)grab((size_t)N * N * 2);     // U = exp(S - 4)
  float*    part  = (float*)grab((size_t)N * 64 * sizeof(float));
  float*    invL  = (float*)grab((size_t)N * sizeof(float));
  float*    bcat  = (float*)grab((size_t)2 * D * sizeof(float));
  // PV split-K partial (z=0): 32 MB aliased over xh/wqkh/wvh/QKcat-head,
  // all dead once gemm_stats_k has run (PV launches after stats).
  float*    pvpart = (float*)d_ws;

  cvt_k<<<N * D / 1024, 256, 0, stream>>>(x,  xh,  N * D);
  cvt_k<<<D * D / 1024, 256, 0, stream>>>(Wq, wqkh,         D * D);
  cvt_k<<<D * D / 1024, 256, 0, stream>>>(Wk, wqkh + D * D, D * D);
  cvt_k<<<D * D / 1024, 256, 0, stream>>>(Wv, wvh, D * D);
  hipMemcpyAsync(bcat,     bq, D * sizeof(float), hipMemcpyDeviceToDevice, stream);
  hipMemcpyAsync(bcat + D, bk, D * sizeof(float), hipMemcpyDeviceToDevice, stream);

  dim3 blk(256);
  // [Q | K] = x [Wq;Wk]^T + [bq|bk]   (unscaled; 1/32 folded into stats)
  gemm_bt_k<1, 0, 0><<<dim3(2 * D / 128, N / 128), blk, 0, stream>>>(
      xh, wqkh, QKcat, bcat, D, D, 2 * D, D, 1.0f, 0);
  // V^T = Wv x^T + bv (bias per output row = per channel d)
  gemm_bt_k<2, 0, 0><<<dim3(N / 128, D / 128), blk, 0, stream>>>(
      wvh, xh, VTh, bv, D, D, N, D, 1.0f, 0);
  // U = exp(QK^T/32 + decay - 4) + partial row sums (BK=64 swizzled)
  gemm_stats_k<<<dim3(N / 128, N / 128), blk, 0, stream>>>(
      QKcat, QKcat + D, ts, Uh, part, 2 * D, 2 * D, N, D, 1.0f / 32.0f);
  combine_k<<<N / 256, 256, 0, stream>>>(part, invL);
  // O_partial = U V, split-K=2: z0 -> pvpart, z1 -> d_out (zByteStride jumps
  // between the two buffers); XCD-swizzled; invL applied in reduce.
  const long long zbs = (long long)((char*)d_out - (char*)pvpart);
  gemm_bt_k<0, 2, 1><<<dim3(D / 128, N / 128, 2), blk, 0, stream>>>(
      Uh, VTh, pvpart, nullptr, N, N, D, N / 2, 1.0f, zbs);
  // out = (out + pvpart) * invL
  reduce_k<<<(N * D) / 1024, 256, 0, stream>>>((float*)d_out, pvpart, invL);
}

// Round 7
// 500.485 us; speedup vs baseline: 1.2052x; 1.2052x over previous
//
#include <hip/hip_runtime.h>

// TemporalAttention N=8192 D=1024, fp32 in/out, fp16-MFMA internals.
// v7: all GEMMs on the BK=64 XOR-swizzled K-loop (validated in v6's stats):
// LDS chunk c holds global chunk c^(row&7), making frag ds_read_b128 2-way
// bank-aliased (free) instead of 8-way (2.9x). PV split-K reverted (measured
// neutral+overhead); invL applied in PV epilogue; reduce kernel deleted.

using half8   = __attribute__((ext_vector_type(8))) _Float16;
using half4   = __attribute__((ext_vector_type(4))) _Float16;
using floatx4 = __attribute__((ext_vector_type(4))) float;

__device__ __forceinline__ void gload_lds16(const void* g, void* l) {
  __builtin_amdgcn_global_load_lds((const __attribute__((address_space(1))) void*)g,
                                   (__attribute__((address_space(3))) void*)l,
                                   16, 0, 0);
}

// C[128y.., 128x..] = A(rows, lda) * B(rows, ldb)^T; fp16 in, fp32 accum.
// 128x128 tile, BK=64 XOR-swizzled LDS, 4 waves of 4x4 16x16x32 MFMA,
// 2 k-subiters per staging round.
// BIAS_MODE: 0 none, 1 add per-col, 2 add per-row, 3 MUL per-row (invL).
// OUT_MODE: 0 fp16, 2 fp32.  SWZ: tileY = bflat % gridDim.y (XCD grouping).
template<int BIAS_MODE, int OUT_MODE, int SWZ>
__global__ __launch_bounds__(256)
void gemm64_k(const _Float16* __restrict__ A, const _Float16* __restrict__ B,
              void* __restrict__ Cout, const float* __restrict__ bias,
              int lda, int ldb, int ldc, int K, float outScale)
{
  __shared__ __align__(16) _Float16 As[128 * 64];
  __shared__ __align__(16) _Float16 Bs[128 * 64];
  const int tid = threadIdx.x;
  const int w = tid >> 6, lane = tid & 63;
  const int q = lane >> 4, l15 = lane & 15;
  const int wr = w >> 1, wc = w & 1;

  int tx, ty;
  if (SWZ) {
    const int bflat = blockIdx.y * gridDim.x + blockIdx.x;  // dispatch-linear
    ty = bflat % gridDim.y;          // same ty -> same bflat%8 -> same XCD
    tx = bflat / gridDim.y;
  } else {
    tx = blockIdx.x; ty = blockIdx.y;
  }
  const long rowBase = (long)ty * 128;
  const long colBase = (long)tx * 128;

  // staging: 4 passes/wave/operand; lane elem e = w*2048 + p*512 + lane*8;
  // row = e/64, chunk = (e/8)&7; source chunk = chunk ^ (row&7).
  const _Float16* Ag[4]; const _Float16* Bg[4];
  _Float16* Al[4]; _Float16* Bl[4];
#pragma unroll
  for (int p = 0; p < 4; ++p) {
    const int e = w * 2048 + p * 512 + lane * 8;
    const int row = e >> 6, c = (e >> 3) & 7;
    const int sc = (c ^ (row & 7)) << 3;
    Ag[p] = A + (rowBase + row) * lda + sc;
    Bg[p] = B + (colBase + row) * ldb + sc;
    Al[p] = &As[w * 2048 + p * 512];
    Bl[p] = &Bs[w * 2048 + p * 512];
  }

  floatx4 acc[4][4] = {};

  for (int k0 = 0; k0 < K; k0 += 64) {
    __syncthreads();
#pragma unroll
    for (int p = 0; p < 4; ++p) {
      gload_lds16(Ag[p], Al[p]);
      gload_lds16(Bg[p], Bl[p]);
      Ag[p] += 64; Bg[p] += 64;
    }
    __syncthreads();
#pragma unroll
    for (int kk = 0; kk < 2; ++kk) {
      half8 b[4];
#pragma unroll
      for (int j = 0; j < 4; ++j) {
        const int R = wc * 64 + 16 * j + l15;
        b[j] = *(const half8*)&Bs[R * 64 + (((kk * 4 + q) ^ (R & 7)) << 3)];
      }
#pragma unroll
      for (int i = 0; i < 4; ++i) {
        const int R = wr * 64 + 16 * i + l15;
        const half8 a = *(const half8*)&As[R * 64 + (((kk * 4 + q) ^ (R & 7)) << 3)];
#pragma unroll
        for (int j = 0; j < 4; ++j)
          acc[i][j] = __builtin_amdgcn_mfma_f32_16x16x32_f16(a, b[j], acc[i][j], 0, 0, 0);
      }
    }
  }

#pragma unroll
  for (int i = 0; i < 4; ++i) {
#pragma unroll
    for (int r = 0; r < 4; ++r) {
      const long rowg = rowBase + wr * 64 + 16 * i + q * 4 + r;
#pragma unroll
      for (int j = 0; j < 4; ++j) {
        const long colg = colBase + wc * 64 + 16 * j + l15;
        float v = acc[i][j][r];
        if (BIAS_MODE == 1) v += bias[colg];
        if (BIAS_MODE == 2) v += bias[rowg];
        if (BIAS_MODE == 3) v *= bias[rowg];
        v *= outScale;
        if (OUT_MODE == 2) ((float*)Cout)[rowg * ldc + colg] = v;
        else               ((_Float16*)Cout)[rowg * ldc + colg] = (_Float16)v;
      }
    }
  }
}

// U = exp(qkScale*(Q*K^T) + decay_bias - 4), fp16; per-(row,col-tile) sums.
// BK=64, XOR-swizzled LDS (same K-loop as gemm64_k). Validated in v6.
__global__ __launch_bounds__(256)
void gemm_stats_k(const _Float16* __restrict__ A, const _Float16* __restrict__ B,
                  const float* __restrict__ ts, _Float16* __restrict__ U,
                  float* __restrict__ part, int lda, int ldb, int N, int K,
                  float qkScale)
{
  __shared__ __align__(16) _Float16 As[128 * 64];
  __shared__ __align__(16) _Float16 Bs[128 * 64];
  __shared__ float trs[128], tcs[128];
  __shared__ float sL[2][2][64];
  const int tid = threadIdx.x;
  const int w = tid >> 6, lane = tid & 63;
  const int q = lane >> 4, l15 = lane & 15;
  const int wr = w >> 1, wc = w & 1;
  const long rowBase = (long)blockIdx.y * 128;
  const long colBase = (long)blockIdx.x * 128;

  if (tid < 128) {
    trs[tid] = ts[rowBase + tid];
    tcs[tid] = ts[colBase + tid];
  }

  const _Float16* Ag[4]; const _Float16* Bg[4];
  _Float16* Al[4]; _Float16* Bl[4];
#pragma unroll
  for (int p = 0; p < 4; ++p) {
    const int e = w * 2048 + p * 512 + lane * 8;
    const int row = e >> 6, c = (e >> 3) & 7;
    const int sc = (c ^ (row & 7)) << 3;
    Ag[p] = A + (rowBase + row) * lda + sc;
    Bg[p] = B + (colBase + row) * ldb + sc;
    Al[p] = &As[w * 2048 + p * 512];
    Bl[p] = &Bs[w * 2048 + p * 512];
  }

  floatx4 acc[4][4] = {};

  for (int k0 = 0; k0 < K; k0 += 64) {
    __syncthreads();
#pragma unroll
    for (int p = 0; p < 4; ++p) {
      gload_lds16(Ag[p], Al[p]);
      gload_lds16(Bg[p], Bl[p]);
      Ag[p] += 64; Bg[p] += 64;
    }
    __syncthreads();
#pragma unroll
    for (int kk = 0; kk < 2; ++kk) {
      half8 b[4];
#pragma unroll
      for (int j = 0; j < 4; ++j) {
        const int R = wc * 64 + 16 * j + l15;
        b[j] = *(const half8*)&Bs[R * 64 + (((kk * 4 + q) ^ (R & 7)) << 3)];
      }
#pragma unroll
      for (int i = 0; i < 4; ++i) {
        const int R = wr * 64 + 16 * i + l15;
        const half8 a = *(const half8*)&As[R * 64 + (((kk * 4 + q) ^ (R & 7)) << 3)];
#pragma unroll
        for (int j = 0; j < 4; ++j)
          acc[i][j] = __builtin_amdgcn_mfma_f32_16x16x32_f16(a, b[j], acc[i][j], 0, 0, 0);
      }
    }
  }

  const float inv_td = 1.0f / 86400.0f;
  // u = exp(s - 4); s = qk/32 + log-decay ~ qk/32 - |dt|/TD (exact to 2.2e-6).
#pragma unroll
  for (int i = 0; i < 4; ++i) {
#pragma unroll
    for (int r = 0; r < 4; ++r) {
      const int rowl = wr * 64 + 16 * i + q * 4 + r;
      float ls = 0.0f;
#pragma unroll
      for (int j = 0; j < 4; ++j) {
        const int coll = wc * 64 + 16 * j + l15;
        const float sv = acc[i][j][r] * qkScale
                       - fabsf(trs[rowl] - tcs[coll]) * inv_td - 4.0f;
        const float u = __expf(sv);
        ls += u;
        U[(rowBase + rowl) * (long)N + (colBase + coll)] = (_Float16)u;
      }
      for (int mask = 1; mask <= 8; mask <<= 1)
        ls += __shfl_xor(ls, mask, 64);
      if (l15 == 0) sL[wr][wc][16 * i + 4 * q + r] = ls;
    }
  }
  __syncthreads();
  if (tid < 128) {
    const int wr2 = tid >> 6, rl = tid & 63;
    part[(rowBase + tid) * 64 + blockIdx.x] = sL[wr2][0][rl] + sL[wr2][1][rl];
  }
}

__global__ void combine_k(const float* __restrict__ part, float* __restrict__ invL) {
  const int r = blockIdx.x * 256 + threadIdx.x;
  float L = 0.0f;
  for (int c = 0; c < 64; ++c) L += part[(long)r * 64 + c];
  invL[r] = 1.0f / L;
}

// fp32 -> fp16, 4/thread
__global__ void cvt_k(const float* __restrict__ in, _Float16* __restrict__ out, int n) {
  const int i = (blockIdx.x * 256 + threadIdx.x) * 4;
  if (i >= n) return;
  const float4 v = *(const float4*)(in + i);
  half4 o = { (_Float16)v.x, (_Float16)v.y, (_Float16)v.z, (_Float16)v.w };
  *(half4*)(out + i) = o;
}

extern "C" void kernel_launch(void* const* d_in, const int* in_sizes, int n_in,
                              void* d_out, int out_size, void* d_ws, size_t ws_size,
                              hipStream_t stream)
{
  (void)in_sizes; (void)n_in; (void)out_size; (void)ws_size;
  const int N = 8192, D = 1024;
  const float* x  = (const float*)d_in[0];
  const float* ts = (const float*)d_in[1];
  const float* Wq = (const float*)d_in[2];
  const float* bq = (const float*)d_in[3];
  const float* Wk = (const float*)d_in[4];
  const float* bk = (const float*)d_in[5];
  const float* Wv = (const float*)d_in[6];
  const float* bv = (const float*)d_in[7];

  char* p = (char*)d_ws;
  auto grab = [&](size_t bytes) {
    char* r = p;
    p += (bytes + 255) & ~(size_t)255;
    return r;
  };
  _Float16* xh    = (_Float16*)grab((size_t)N * D * 2);
  _Float16* wqkh  = (_Float16*)grab((size_t)2 * D * D * 2); // Wq rows then Wk rows
  _Float16* wvh   = (_Float16*)grab((size_t)D * D * 2);
  _Float16* QKcat = (_Float16*)grab((size_t)N * 2 * D * 2); // [N x 2D], Q | K
  _Float16* VTh   = (_Float16*)grab((size_t)D * N * 2);     // V^T [D x N]
  _Float16* Uh    = (_Float16*)grab((size_t)N * N * 2);     // U = exp(S - 4)
  float*    part  = (float*)grab((size_t)N * 64 * sizeof(float));
  float*    invL  = (float*)grab((size_t)N * sizeof(float));
  float*    bcat  = (float*)grab((size_t)2 * D * sizeof(float));

  cvt_k<<<N * D / 1024, 256, 0, stream>>>(x,  xh,  N * D);
  cvt_k<<<D * D / 1024, 256, 0, stream>>>(Wq, wqkh,         D * D);
  cvt_k<<<D * D / 1024, 256, 0, stream>>>(Wk, wqkh + D * D, D * D);
  cvt_k<<<D * D / 1024, 256, 0, stream>>>(Wv, wvh, D * D);
  hipMemcpyAsync(bcat,     bq, D * sizeof(float), hipMemcpyDeviceToDevice, stream);
  hipMemcpyAsync(bcat + D, bk, D * sizeof(float), hipMemcpyDeviceToDevice, stream);

  dim3 blk(256);
  // [Q | K] = x [Wq;Wk]^T + [bq|bk]   (unscaled; 1/32 folded into stats)
  gemm64_k<1, 0, 0><<<dim3(2 * D / 128, N / 128), blk, 0, stream>>>(
      xh, wqkh, QKcat, bcat, D, D, 2 * D, D, 1.0f);
  // V^T = Wv x^T + bv (bias per output row = per channel d)
  gemm64_k<2, 0, 0><<<dim3(N / 128, D / 128), blk, 0, stream>>>(
      wvh, xh, VTh, bv, D, D, N, D, 1.0f);
  // U = exp(QK^T/32 + decay - 4) + partial row sums (BK=64 swizzled)
  gemm_stats_k<<<dim3(N / 128, N / 128), blk, 0, stream>>>(
      QKcat, QKcat + D, ts, Uh, part, 2 * D, 2 * D, N, D, 1.0f / 32.0f);
  combine_k<<<N / 256, 256, 0, stream>>>(part, invL);
  // O = (U V) * invL — XCD-swizzled; conflict-free BK=64 loop
  gemm64_k<3, 2, 1><<<dim3(D / 128, N / 128), blk, 0, stream>>>(
      Uh, VTh, d_out, invL, N, N, D, N, 1.0f);
}